// Round 7
// baseline (1858.318 us; speedup 1.0000x reference)
//
#include <hip/hip_runtime.h>
#include <hip/hip_bf16.h>
#include <math.h>
#include <stdint.h>

#define N_NODES 100000
#define N_EDGES 3200000
#define D 64
#define NUM_RELS 20
#define HID_ATTR 32
#define OUT_ATTR 10
#define NKEYS (N_NODES * NUM_RELS)       // 2,000,000 sort bins (dst*20+rel)
#define SCAN2_B 7813                     // ceil(NKEYS / 256)
#define PADR 72                          // A-tile row stride in bf16 (144 B, 16B-aligned)

typedef __attribute__((ext_vector_type(8))) short bf16x8;
typedef __attribute__((ext_vector_type(4))) float f32x4;

static __device__ __forceinline__ unsigned short f2bf(float x) {
    unsigned u = __builtin_bit_cast(unsigned, x);
    unsigned r = (u + 0x7FFFu + ((u >> 16) & 1u)) >> 16;
    return (unsigned short)r;
}
static __device__ __forceinline__ float bf2f(unsigned short b) {
    return __builtin_bit_cast(float, (unsigned)b << 16);
}

// ---------------- CSR build: counting sort by key = dst*20 + rel ----------------

__global__ void deg_count2(const int* __restrict__ dst, const int* __restrict__ etype,
                           int* __restrict__ deg2) {
    int e = blockIdx.x * 256 + threadIdx.x;
    atomicAdd(&deg2[dst[e] * NUM_RELS + etype[e]], 1);
}

__global__ void scan2_bsum(const int* __restrict__ deg2, int* __restrict__ bsum) {
    __shared__ int s[256];
    int t = threadIdx.x, i = blockIdx.x * 256 + t;
    s[t] = (i < NKEYS) ? deg2[i] : 0;
    __syncthreads();
    for (int d2 = 128; d2 > 0; d2 >>= 1) {
        if (t < d2) s[t] += s[t + d2];
        __syncthreads();
    }
    if (t == 0) bsum[blockIdx.x] = s[0];
}

__global__ void scan2_bbase(const int* __restrict__ bsum, int* __restrict__ bbase,
                            int* __restrict__ off2) {
    __shared__ int s[1024];
    int t = threadIdx.x;
    int loc[8];
    int sum = 0;
    int b0 = t * 8;
#pragma unroll
    for (int j = 0; j < 8; ++j) {
        int b = b0 + j;
        int v = (b < SCAN2_B) ? bsum[b] : 0;
        loc[j] = sum; sum += v;
    }
    s[t] = sum;
    __syncthreads();
    for (int d2 = 1; d2 < 1024; d2 <<= 1) {
        int x = (t >= d2) ? s[t - d2] : 0;
        __syncthreads();
        s[t] += x;
        __syncthreads();
    }
    int base = (t > 0) ? s[t - 1] : 0;
#pragma unroll
    for (int j = 0; j < 8; ++j) {
        int b = b0 + j;
        if (b < SCAN2_B) bbase[b] = base + loc[j];
    }
    if (t == 0) off2[NKEYS] = N_EDGES;
}

__global__ void scan2_final(const int* __restrict__ deg2, const int* __restrict__ bbase,
                            int* __restrict__ off2, int* __restrict__ cur2) {
    __shared__ int s[256];
    int t = threadIdx.x, i = blockIdx.x * 256 + t;
    int v = (i < NKEYS) ? deg2[i] : 0;
    s[t] = v;
    __syncthreads();
    for (int d2 = 1; d2 < 256; d2 <<= 1) {
        int x = (t >= d2) ? s[t - d2] : 0;
        __syncthreads();
        s[t] += x;
        __syncthreads();
    }
    if (i < NKEYS) {
        int e = bbase[blockIdx.x] + s[t] - v;
        off2[i] = e; cur2[i] = e;
    }
}

// pack (src, rel): src < 2^17, rel < 2^5
__global__ void scatter_edges2(const int* __restrict__ src, const int* __restrict__ dst,
                               const int* __restrict__ etype, int* __restrict__ cur2,
                               int* __restrict__ edgedata) {
    int e = blockIdx.x * 256 + threadIdx.x;
    int key = dst[e] * NUM_RELS + etype[e];
    int pos = atomicAdd(&cur2[key], 1);
    edgedata[pos] = src[e] | (etype[e] << 17);
}

// ---------------- dtype conversions ----------------

__global__ void f2b_kernel(const float* __restrict__ in, unsigned short* __restrict__ out,
                           int n4) {
    int i = blockIdx.x * 256 + threadIdx.x;
    if (i >= n4) return;
    float4 v = ((const float4*)in)[i];
    ushort4 o;
    o.x = f2bf(v.x); o.y = f2bf(v.y); o.z = f2bf(v.z); o.w = f2bf(v.w);
    ((ushort4*)out)[i] = o;
}

// W[r][d][o] fp32 -> Wb[r][o][d] bf16 (B-frag layout, verified round 4)
__global__ void wconv_kernel(const float* __restrict__ W, unsigned short* __restrict__ Wb) {
    int r = blockIdx.x;
    for (int i = threadIdx.x; i < D * D; i += 256) {
        int d2 = i >> 6, o = i & 63;
        Wb[(size_t)r * (D * D) + o * D + d2] = f2bf(W[(size_t)r * (D * D) + d2 * D + o]);
    }
}

// ---------------- fused layer: gather pair-sums into LDS, MFMA, write h ----------------
// Block = 16 dst nodes. Wave w gathers dsts w*4..w*4+3 (rel-grouped CSR lists,
// register fp32 acc, one bf16 flush per (dst,rel) run -> LDS A-tile).
// Then wave w computes output cols w*16..w*16+15: one 16x16 C over 20 rels
// (40 MFMAs), using round-4-verified A/B/C fragment layouts.
// mode 1: write relu'd bf16 to xbout;  mode 2: write fp32 to h2out.
__global__ __launch_bounds__(256) void fused_layer(
    const unsigned short* __restrict__ xb, const unsigned short* __restrict__ Wb,
    const int* __restrict__ edgedata, const int* __restrict__ off2,
    unsigned short* __restrict__ xbout, float* __restrict__ h2out, int mode) {
    __shared__ __align__(16) unsigned short A[NUM_RELS * 16 * PADR];  // 46080 B
    int wave = threadIdx.x >> 6, lane = threadIdx.x & 63;

    // zero A-tile (covers empty (dst,rel) pairs)
    for (int i = threadIdx.x; i < NUM_RELS * 16 * PADR / 8; i += 256)
        ((int4*)A)[i] = (int4){0, 0, 0, 0};
    __syncthreads();

    int n0 = blockIdx.x * 16;
    for (int dl = 0; dl < 4; ++dl) {
        int m = wave * 4 + dl;                 // row in tile
        int v = n0 + m;                        // dst node
        int beg = off2[v * NUM_RELS];
        int end = off2[v * NUM_RELS + NUM_RELS];
        float acc = 0.f;
        int qcur = -1;
        for (int i = beg; i < end; ++i) {
            int ew = __builtin_amdgcn_readfirstlane(edgedata[i]);
            int q = ew >> 17;
            if (q != qcur) {                   // wave-uniform branch
                if (qcur >= 0) A[(qcur * 16 + m) * PADR + lane] = f2bf(acc);
                acc = 0.f; qcur = q;
            }
            acc += bf2f(xb[(size_t)(ew & 0x1FFFF) * D + lane]);
        }
        if (qcur >= 0) A[(qcur * 16 + m) * PADR + lane] = f2bf(acc);
    }
    __syncthreads();

    int lrow = lane & 15, lhi = lane >> 4;
    f32x4 C = {0.f, 0.f, 0.f, 0.f};
    for (int q = 0; q < NUM_RELS; ++q) {
        const unsigned short* Arow = &A[(q * 16 + lrow) * PADR + lhi * 8];
        bf16x8 a0 = *(const bf16x8*)(Arow);         // k = lhi*8 + j
        bf16x8 a1 = *(const bf16x8*)(Arow + 32);    // k = 32 + lhi*8 + j
        const unsigned short* wrow = Wb + ((size_t)q << 12)
                                     + (size_t)(wave * 16 + lrow) * D + lhi * 8;
        bf16x8 b0 = *(const bf16x8*)(wrow);
        bf16x8 b1 = *(const bf16x8*)(wrow + 32);
        C = __builtin_amdgcn_mfma_f32_16x16x32_bf16(a0, b0, C, 0, 0, 0);
        C = __builtin_amdgcn_mfma_f32_16x16x32_bf16(a1, b1, C, 0, 0, 0);
    }
    // C/D: row = lhi*4 + reg (dst-local), col = wave*16 + lrow
#pragma unroll
    for (int reg = 0; reg < 4; ++reg) {
        int node = n0 + lhi * 4 + reg;
        int col = wave * 16 + lrow;
        if (mode == 1)
            xbout[(size_t)node * D + col] = f2bf(fmaxf(C[reg], 0.f));
        else
            h2out[(size_t)node * D + col] = C[reg];
    }
}

// ---------------- readout ----------------

__global__ void colsum_kernel(const float* __restrict__ h2,
                              float* __restrict__ g, int n) {
    __shared__ float s[256];
    int tid = threadIdx.x;
    int col = tid & 63;
    int rowgrp = (blockIdx.x * blockDim.x + tid) >> 6;
    int nrowgrp = (gridDim.x * blockDim.x) >> 6;
    float acc = 0.0f;
    for (int row = rowgrp; row < n; row += nrowgrp)
        acc += h2[(size_t)row * D + col];
    s[tid] = acc;
    __syncthreads();
    if (tid < 64) {
        acc = s[tid] + s[tid + 64] + s[tid + 128] + s[tid + 192];
        atomicAdd(&g[col], acc);
    }
}

__global__ void mlp_kernel(const float* __restrict__ g,
                           const float* __restrict__ A1w,
                           const float* __restrict__ A1b,
                           const float* __restrict__ A2w,
                           const float* __restrict__ A2b,
                           float* __restrict__ out, float invN) {
    __shared__ float a1[HID_ATTR];
    int t = threadIdx.x;
    if (t < HID_ATTR) {
        float acc = A1b[t];
#pragma unroll
        for (int d2 = 0; d2 < D; ++d2)
            acc = fmaf(g[d2] * invN, A1w[d2 * HID_ATTR + t], acc);
        a1[t] = fmaxf(acc, 0.0f);
    }
    __syncthreads();
    if (t < OUT_ATTR) {
        float acc = A2b[t];
#pragma unroll
        for (int j = 0; j < HID_ATTR; ++j)
            acc = fmaf(a1[j], A2w[j * OUT_ATTR + t], acc);
        out[t] = 1.0f / (1.0f + expf(-acc));
    }
}

// ---------------- launch ----------------

extern "C" void kernel_launch(void* const* d_in, const int* in_sizes, int n_in,
                              void* d_out, int out_size, void* d_ws, size_t ws_size,
                              hipStream_t stream) {
    const float* h   = (const float*)d_in[0];
    const int* src   = (const int*)d_in[1];
    const int* dst   = (const int*)d_in[2];
    const int* etype = (const int*)d_in[3];
    const float* W1  = (const float*)d_in[4];
    const float* W2  = (const float*)d_in[5];
    const float* A1w = (const float*)d_in[6];
    const float* A1b = (const float*)d_in[7];
    const float* A2w = (const float*)d_in[8];
    const float* A2b = (const float*)d_in[9];

    float* out_h2 = (float*)d_out;
    float* out_a  = out_h2 + (size_t)N_NODES * D;

    // workspace layout (int offsets from d_ws; all buffers 16B-aligned)
    int* base     = (int*)d_ws;
    float* gsum   = (float*)base;                 // 64 f32
    int* deg2     = base + 64;                    // 2,000,000
    int* off2     = base + 2000064;               // 2,000,001 (pad to 2,000,064)
    int* cur2     = base + 4000128;               // 2,000,000
    int* bsum2    = base + 6000128;               // 7,813 (pad 7,872)
    int* bbase2   = base + 6008000;               // 7,872
    int* edgedata = base + 6015872;               // 3,200,000
    unsigned short* xb  = (unsigned short*)(base + 9215872);   // 6.4M u16
    unsigned short* xb2 = (unsigned short*)(base + 12415872);  // 6.4M u16
    unsigned short* w1b = (unsigned short*)(base + 15615872);  // 81,920 u16
    unsigned short* w2b = (unsigned short*)(base + 15656832);  // 81,920 u16
    // total: 15,697,792 ints = 62.8 MB

    hipMemsetAsync(deg2, 0, (size_t)NKEYS * sizeof(int), stream);
    hipMemsetAsync(gsum, 0, 64 * sizeof(float), stream);

    // CSR sorted by (dst, rel)
    deg_count2<<<N_EDGES / 256, 256, 0, stream>>>(dst, etype, deg2);
    scan2_bsum<<<SCAN2_B, 256, 0, stream>>>(deg2, bsum2);
    scan2_bbase<<<1, 1024, 0, stream>>>(bsum2, bbase2, off2);
    scan2_final<<<SCAN2_B, 256, 0, stream>>>(deg2, bbase2, off2, cur2);
    scatter_edges2<<<N_EDGES / 256, 256, 0, stream>>>(src, dst, etype, cur2, edgedata);

    // conversions
    wconv_kernel<<<NUM_RELS, 256, 0, stream>>>(W1, w1b);
    wconv_kernel<<<NUM_RELS, 256, 0, stream>>>(W2, w2b);
    f2b_kernel<<<(N_NODES * D / 4 + 255) / 256, 256, 0, stream>>>(h, xb, N_NODES * D / 4);

    // two fused RGCN layers
    fused_layer<<<N_NODES / 16, 256, 0, stream>>>(xb, w1b, edgedata, off2,
                                                  xb2, nullptr, 1);
    fused_layer<<<N_NODES / 16, 256, 0, stream>>>(xb2, w2b, edgedata, off2,
                                                  nullptr, out_h2, 2);

    // readout
    colsum_kernel<<<512, 256, 0, stream>>>(out_h2, gsum, N_NODES);
    mlp_kernel<<<1, 64, 0, stream>>>(gsum, A1w, A1b, A2w, A2b,
                                     out_a, 1.0f / (float)N_NODES);
}

// Round 8
// 1187.317 us; speedup vs baseline: 1.5651x; 1.5651x over previous
//
#include <hip/hip_runtime.h>
#include <hip/hip_bf16.h>
#include <math.h>
#include <stdint.h>

#define N_NODES 100000
#define N_EDGES 3200000
#define D 64
#define NUM_RELS 20
#define HID_ATTR 32
#define OUT_ATTR 10
#define NKEYS (N_NODES * NUM_RELS)       // 2,000,000 sort bins (dst*20+rel)
#define SCAN2_B 7813                     // ceil(NKEYS / 256)
#define PADR 72                          // A-tile row stride in bf16 (144 B, 16B-aligned)

typedef __attribute__((ext_vector_type(8))) short bf16x8;
typedef __attribute__((ext_vector_type(4))) float f32x4;

static __device__ __forceinline__ unsigned short f2bf(float x) {
    unsigned u = __builtin_bit_cast(unsigned, x);
    unsigned r = (u + 0x7FFFu + ((u >> 16) & 1u)) >> 16;
    return (unsigned short)r;
}
static __device__ __forceinline__ float bf2f(unsigned short b) {
    return __builtin_bit_cast(float, (unsigned)b << 16);
}

// ---------------- CSR build: counting sort by key = dst*20 + rel ----------------

__global__ void deg_count2(const int* __restrict__ dst, const int* __restrict__ etype,
                           int* __restrict__ deg2) {
    int e = blockIdx.x * 256 + threadIdx.x;
    atomicAdd(&deg2[dst[e] * NUM_RELS + etype[e]], 1);
}

__global__ void scan2_bsum(const int* __restrict__ deg2, int* __restrict__ bsum) {
    __shared__ int s[256];
    int t = threadIdx.x, i = blockIdx.x * 256 + t;
    s[t] = (i < NKEYS) ? deg2[i] : 0;
    __syncthreads();
    for (int d2 = 128; d2 > 0; d2 >>= 1) {
        if (t < d2) s[t] += s[t + d2];
        __syncthreads();
    }
    if (t == 0) bsum[blockIdx.x] = s[0];
}

__global__ void scan2_bbase(const int* __restrict__ bsum, int* __restrict__ bbase,
                            int* __restrict__ off2) {
    __shared__ int s[1024];
    int t = threadIdx.x;
    int loc[8];
    int sum = 0;
    int b0 = t * 8;
#pragma unroll
    for (int j = 0; j < 8; ++j) {
        int b = b0 + j;
        int v = (b < SCAN2_B) ? bsum[b] : 0;
        loc[j] = sum; sum += v;
    }
    s[t] = sum;
    __syncthreads();
    for (int d2 = 1; d2 < 1024; d2 <<= 1) {
        int x = (t >= d2) ? s[t - d2] : 0;
        __syncthreads();
        s[t] += x;
        __syncthreads();
    }
    int base = (t > 0) ? s[t - 1] : 0;
#pragma unroll
    for (int j = 0; j < 8; ++j) {
        int b = b0 + j;
        if (b < SCAN2_B) bbase[b] = base + loc[j];
    }
    if (t == 0) off2[NKEYS] = N_EDGES;
}

__global__ void scan2_final(const int* __restrict__ deg2, const int* __restrict__ bbase,
                            int* __restrict__ off2, int* __restrict__ cur2) {
    __shared__ int s[256];
    int t = threadIdx.x, i = blockIdx.x * 256 + t;
    int v = (i < NKEYS) ? deg2[i] : 0;
    s[t] = v;
    __syncthreads();
    for (int d2 = 1; d2 < 256; d2 <<= 1) {
        int x = (t >= d2) ? s[t - d2] : 0;
        __syncthreads();
        s[t] += x;
        __syncthreads();
    }
    if (i < NKEYS) {
        int e = bbase[blockIdx.x] + s[t] - v;
        off2[i] = e; cur2[i] = e;
    }
}

// pack (src, rel): src < 2^17, rel < 2^5
__global__ void scatter_edges2(const int* __restrict__ src, const int* __restrict__ dst,
                               const int* __restrict__ etype, int* __restrict__ cur2,
                               int* __restrict__ edgedata) {
    int e = blockIdx.x * 256 + threadIdx.x;
    int key = dst[e] * NUM_RELS + etype[e];
    int pos = atomicAdd(&cur2[key], 1);
    edgedata[pos] = src[e] | (etype[e] << 17);
}

// ---------------- dtype conversions ----------------

__global__ void f2b_kernel(const float* __restrict__ in, unsigned short* __restrict__ out,
                           int n4) {
    int i = blockIdx.x * 256 + threadIdx.x;
    if (i >= n4) return;
    float4 v = ((const float4*)in)[i];
    ushort4 o;
    o.x = f2bf(v.x); o.y = f2bf(v.y); o.z = f2bf(v.z); o.w = f2bf(v.w);
    ((ushort4*)out)[i] = o;
}

// W[r][d][o] fp32 -> Wb[r][o][d] bf16 (B-frag layout, verified round 4)
__global__ void wconv_kernel(const float* __restrict__ W, unsigned short* __restrict__ Wb) {
    int r = blockIdx.x;
    for (int i = threadIdx.x; i < D * D; i += 256) {
        int d2 = i >> 6, o = i & 63;
        Wb[(size_t)r * (D * D) + o * D + d2] = f2bf(W[(size_t)r * (D * D) + d2 * D + o]);
    }
}

// ---------------- fused layer: gather pair-sums into LDS, MFMA, write h ----------------
// Block = 16 dst nodes. Wave w gathers dsts w*4..w*4+3 (rel-grouped CSR lists).
// 8-unrolled edge walk: 8 independent xb row loads issued before the
// (wave-uniform, LDS-only) run-flush logic -> 8 loads in flight per wave.
// fp32 register accumulation, one bf16 flush per (dst,rel) run (same numerics
// as round 6/7). Then wave w computes output cols w*16..15 via 40 MFMAs.
// mode 1: write relu'd bf16 to xbout;  mode 2: write fp32 to h2out.
__global__ __launch_bounds__(256) void fused_layer(
    const unsigned short* __restrict__ xb, const unsigned short* __restrict__ Wb,
    const int* __restrict__ edgedata, const int* __restrict__ off2,
    unsigned short* __restrict__ xbout, float* __restrict__ h2out, int mode) {
    __shared__ __align__(16) unsigned short A[NUM_RELS * 16 * PADR];  // 46080 B
    int wave = threadIdx.x >> 6, lane = threadIdx.x & 63;

    // zero A-tile (covers empty (dst,rel) pairs)
    for (int i = threadIdx.x; i < NUM_RELS * 16 * PADR / 8; i += 256)
        ((int4*)A)[i] = (int4){0, 0, 0, 0};
    __syncthreads();

    int n0 = blockIdx.x * 16;
    for (int dl = 0; dl < 4; ++dl) {
        int m = wave * 4 + dl;                 // row in tile
        int v = n0 + m;                        // dst node
        int beg = off2[v * NUM_RELS];
        int end = off2[v * NUM_RELS + NUM_RELS];
        float acc = 0.f;
        int qcur = -1;
        int i = beg;
        for (; i + 7 < end; i += 8) {
            int ew[8];
#pragma unroll
            for (int j = 0; j < 8; ++j)
                ew[j] = __builtin_amdgcn_readfirstlane(edgedata[i + j]);
            float xv[8];
#pragma unroll
            for (int j = 0; j < 8; ++j)
                xv[j] = bf2f(xb[(size_t)(ew[j] & 0x1FFFF) * D + lane]);
#pragma unroll
            for (int j = 0; j < 8; ++j) {
                int q = ew[j] >> 17;
                if (q != qcur) {               // wave-uniform branch, LDS-only body
                    if (qcur >= 0) A[(qcur * 16 + m) * PADR + lane] = f2bf(acc);
                    acc = 0.f; qcur = q;
                }
                acc += xv[j];
            }
        }
        for (; i < end; ++i) {
            int ew = __builtin_amdgcn_readfirstlane(edgedata[i]);
            int q = ew >> 17;
            if (q != qcur) {
                if (qcur >= 0) A[(qcur * 16 + m) * PADR + lane] = f2bf(acc);
                acc = 0.f; qcur = q;
            }
            acc += bf2f(xb[(size_t)(ew & 0x1FFFF) * D + lane]);
        }
        if (qcur >= 0) A[(qcur * 16 + m) * PADR + lane] = f2bf(acc);
    }
    __syncthreads();

    int lrow = lane & 15, lhi = lane >> 4;
    f32x4 C = {0.f, 0.f, 0.f, 0.f};
    for (int q = 0; q < NUM_RELS; ++q) {
        const unsigned short* Arow = &A[(q * 16 + lrow) * PADR + lhi * 8];
        bf16x8 a0 = *(const bf16x8*)(Arow);         // k = lhi*8 + j
        bf16x8 a1 = *(const bf16x8*)(Arow + 32);    // k = 32 + lhi*8 + j
        const unsigned short* wrow = Wb + ((size_t)q << 12)
                                     + (size_t)(wave * 16 + lrow) * D + lhi * 8;
        bf16x8 b0 = *(const bf16x8*)(wrow);
        bf16x8 b1 = *(const bf16x8*)(wrow + 32);
        C = __builtin_amdgcn_mfma_f32_16x16x32_bf16(a0, b0, C, 0, 0, 0);
        C = __builtin_amdgcn_mfma_f32_16x16x32_bf16(a1, b1, C, 0, 0, 0);
    }
    // C/D: row = lhi*4 + reg (dst-local), col = wave*16 + lrow
#pragma unroll
    for (int reg = 0; reg < 4; ++reg) {
        int node = n0 + lhi * 4 + reg;
        int col = wave * 16 + lrow;
        if (mode == 1)
            xbout[(size_t)node * D + col] = f2bf(fmaxf(C[reg], 0.f));
        else
            h2out[(size_t)node * D + col] = C[reg];
    }
}

// ---------------- readout ----------------

__global__ void colsum_kernel(const float* __restrict__ h2,
                              float* __restrict__ g, int n) {
    __shared__ float s[256];
    int tid = threadIdx.x;
    int col = tid & 63;
    int rowgrp = (blockIdx.x * blockDim.x + tid) >> 6;
    int nrowgrp = (gridDim.x * blockDim.x) >> 6;
    float acc = 0.0f;
    for (int row = rowgrp; row < n; row += nrowgrp)
        acc += h2[(size_t)row * D + col];
    s[tid] = acc;
    __syncthreads();
    if (tid < 64) {
        acc = s[tid] + s[tid + 64] + s[tid + 128] + s[tid + 192];
        atomicAdd(&g[col], acc);
    }
}

__global__ void mlp_kernel(const float* __restrict__ g,
                           const float* __restrict__ A1w,
                           const float* __restrict__ A1b,
                           const float* __restrict__ A2w,
                           const float* __restrict__ A2b,
                           float* __restrict__ out, float invN) {
    __shared__ float a1[HID_ATTR];
    int t = threadIdx.x;
    if (t < HID_ATTR) {
        float acc = A1b[t];
#pragma unroll
        for (int d2 = 0; d2 < D; ++d2)
            acc = fmaf(g[d2] * invN, A1w[d2 * HID_ATTR + t], acc);
        a1[t] = fmaxf(acc, 0.0f);
    }
    __syncthreads();
    if (t < OUT_ATTR) {
        float acc = A2b[t];
#pragma unroll
        for (int j = 0; j < HID_ATTR; ++j)
            acc = fmaf(a1[j], A2w[j * OUT_ATTR + t], acc);
        out[t] = 1.0f / (1.0f + expf(-acc));
    }
}

// ---------------- launch ----------------

extern "C" void kernel_launch(void* const* d_in, const int* in_sizes, int n_in,
                              void* d_out, int out_size, void* d_ws, size_t ws_size,
                              hipStream_t stream) {
    const float* h   = (const float*)d_in[0];
    const int* src   = (const int*)d_in[1];
    const int* dst   = (const int*)d_in[2];
    const int* etype = (const int*)d_in[3];
    const float* W1  = (const float*)d_in[4];
    const float* W2  = (const float*)d_in[5];
    const float* A1w = (const float*)d_in[6];
    const float* A1b = (const float*)d_in[7];
    const float* A2w = (const float*)d_in[8];
    const float* A2b = (const float*)d_in[9];

    float* out_h2 = (float*)d_out;
    float* out_a  = out_h2 + (size_t)N_NODES * D;

    // workspace layout (int offsets from d_ws; all buffers 16B-aligned)
    int* base     = (int*)d_ws;
    float* gsum   = (float*)base;                 // 64 f32
    int* deg2     = base + 64;                    // 2,000,000
    int* off2     = base + 2000064;               // 2,000,001 (pad to 2,000,064)
    int* cur2     = base + 4000128;               // 2,000,000
    int* bsum2    = base + 6000128;               // 7,813 (pad 7,872)
    int* bbase2   = base + 6008000;               // 7,872
    int* edgedata = base + 6015872;               // 3,200,000
    unsigned short* xb  = (unsigned short*)(base + 9215872);   // 6.4M u16
    unsigned short* xb2 = (unsigned short*)(base + 12415872);  // 6.4M u16
    unsigned short* w1b = (unsigned short*)(base + 15615872);  // 81,920 u16
    unsigned short* w2b = (unsigned short*)(base + 15656832);  // 81,920 u16
    // total: 15,697,792 ints = 62.8 MB

    hipMemsetAsync(deg2, 0, (size_t)NKEYS * sizeof(int), stream);
    hipMemsetAsync(gsum, 0, 64 * sizeof(float), stream);

    // CSR sorted by (dst, rel)
    deg_count2<<<N_EDGES / 256, 256, 0, stream>>>(dst, etype, deg2);
    scan2_bsum<<<SCAN2_B, 256, 0, stream>>>(deg2, bsum2);
    scan2_bbase<<<1, 1024, 0, stream>>>(bsum2, bbase2, off2);
    scan2_final<<<SCAN2_B, 256, 0, stream>>>(deg2, bbase2, off2, cur2);
    scatter_edges2<<<N_EDGES / 256, 256, 0, stream>>>(src, dst, etype, cur2, edgedata);

    // conversions
    wconv_kernel<<<NUM_RELS, 256, 0, stream>>>(W1, w1b);
    wconv_kernel<<<NUM_RELS, 256, 0, stream>>>(W2, w2b);
    f2b_kernel<<<(N_NODES * D / 4 + 255) / 256, 256, 0, stream>>>(h, xb, N_NODES * D / 4);

    // two fused RGCN layers
    fused_layer<<<N_NODES / 16, 256, 0, stream>>>(xb, w1b, edgedata, off2,
                                                  xb2, nullptr, 1);
    fused_layer<<<N_NODES / 16, 256, 0, stream>>>(xb2, w2b, edgedata, off2,
                                                  nullptr, out_h2, 2);

    // readout
    colsum_kernel<<<512, 256, 0, stream>>>(out_h2, gsum, N_NODES);
    mlp_kernel<<<1, 64, 0, stream>>>(gsum, A1w, A1b, A2w, A2b,
                                     out_a, 1.0f / (float)N_NODES);
}

// Round 9
// 986.469 us; speedup vs baseline: 1.8838x; 1.2036x over previous
//
#include <hip/hip_runtime.h>
#include <hip/hip_bf16.h>
#include <math.h>
#include <stdint.h>

#define N_NODES 100000
#define N_EDGES 3200000
#define D 64
#define NUM_RELS 20
#define HID_ATTR 32
#define OUT_ATTR 10
#define NKEYS (N_NODES * NUM_RELS)       // 2,000,000 sort bins (dst*20+rel)
#define SCAN2_B 7813                     // ceil(NKEYS / 256)
#define PADR 72                          // A-tile row stride in bf16 (144 B, 16B-aligned)

typedef __attribute__((ext_vector_type(8))) short bf16x8;
typedef __attribute__((ext_vector_type(4))) float f32x4;

static __device__ __forceinline__ unsigned short f2bf(float x) {
    unsigned u = __builtin_bit_cast(unsigned, x);
    unsigned r = (u + 0x7FFFu + ((u >> 16) & 1u)) >> 16;
    return (unsigned short)r;
}
static __device__ __forceinline__ float bf2f(unsigned short b) {
    return __builtin_bit_cast(float, (unsigned)b << 16);
}

// ---------------- CSR build: counting sort by key = dst*20 + rel ----------------

__global__ void deg_count2(const int* __restrict__ dst, const int* __restrict__ etype,
                           int* __restrict__ deg2) {
    int e = blockIdx.x * 256 + threadIdx.x;
    atomicAdd(&deg2[dst[e] * NUM_RELS + etype[e]], 1);
}

__global__ void scan2_bsum(const int* __restrict__ deg2, int* __restrict__ bsum) {
    __shared__ int s[256];
    int t = threadIdx.x, i = blockIdx.x * 256 + t;
    s[t] = (i < NKEYS) ? deg2[i] : 0;
    __syncthreads();
    for (int d2 = 128; d2 > 0; d2 >>= 1) {
        if (t < d2) s[t] += s[t + d2];
        __syncthreads();
    }
    if (t == 0) bsum[blockIdx.x] = s[0];
}

__global__ void scan2_bbase(const int* __restrict__ bsum, int* __restrict__ bbase,
                            int* __restrict__ off2) {
    __shared__ int s[1024];
    int t = threadIdx.x;
    int loc[8];
    int sum = 0;
    int b0 = t * 8;
#pragma unroll
    for (int j = 0; j < 8; ++j) {
        int b = b0 + j;
        int v = (b < SCAN2_B) ? bsum[b] : 0;
        loc[j] = sum; sum += v;
    }
    s[t] = sum;
    __syncthreads();
    for (int d2 = 1; d2 < 1024; d2 <<= 1) {
        int x = (t >= d2) ? s[t - d2] : 0;
        __syncthreads();
        s[t] += x;
        __syncthreads();
    }
    int base = (t > 0) ? s[t - 1] : 0;
#pragma unroll
    for (int j = 0; j < 8; ++j) {
        int b = b0 + j;
        if (b < SCAN2_B) bbase[b] = base + loc[j];
    }
    if (t == 0) off2[NKEYS] = N_EDGES;
}

__global__ void scan2_final(const int* __restrict__ deg2, const int* __restrict__ bbase,
                            int* __restrict__ off2, int* __restrict__ cur2) {
    __shared__ int s[256];
    int t = threadIdx.x, i = blockIdx.x * 256 + t;
    int v = (i < NKEYS) ? deg2[i] : 0;
    s[t] = v;
    __syncthreads();
    for (int d2 = 1; d2 < 256; d2 <<= 1) {
        int x = (t >= d2) ? s[t - d2] : 0;
        __syncthreads();
        s[t] += x;
        __syncthreads();
    }
    if (i < NKEYS) {
        int e = bbase[blockIdx.x] + s[t] - v;
        off2[i] = e; cur2[i] = e;
    }
}

// pack (src, rel): src < 2^17, rel < 2^5
__global__ void scatter_edges2(const int* __restrict__ src, const int* __restrict__ dst,
                               const int* __restrict__ etype, int* __restrict__ cur2,
                               int* __restrict__ edgedata) {
    int e = blockIdx.x * 256 + threadIdx.x;
    int key = dst[e] * NUM_RELS + etype[e];
    int pos = atomicAdd(&cur2[key], 1);
    edgedata[pos] = src[e] | (etype[e] << 17);
}

// ---------------- dtype conversions ----------------

__global__ void f2b_kernel(const float* __restrict__ in, unsigned short* __restrict__ out,
                           int n4) {
    int i = blockIdx.x * 256 + threadIdx.x;
    if (i >= n4) return;
    float4 v = ((const float4*)in)[i];
    ushort4 o;
    o.x = f2bf(v.x); o.y = f2bf(v.y); o.z = f2bf(v.z); o.w = f2bf(v.w);
    ((ushort4*)out)[i] = o;
}

// W[r][d][o] fp32 -> Wb[r][o][d] bf16 (B-frag layout, verified round 4)
__global__ void wconv_kernel(const float* __restrict__ W, unsigned short* __restrict__ Wb) {
    int r = blockIdx.x;
    for (int i = threadIdx.x; i < D * D; i += 256) {
        int d2 = i >> 6, o = i & 63;
        Wb[(size_t)r * (D * D) + o * D + d2] = f2bf(W[(size_t)r * (D * D) + d2 * D + o]);
    }
}

// ---------------- fused layer ----------------
// Block = 16 dst nodes, 8 waves; wave w gathers dsts {2w, 2w+1}.
// Gather: 8-unrolled, edge-words prefetched one group ahead (VGPRs, no
// readfirstlane -> no early vmcnt wait), BRANCHLESS run accumulation:
//   acc = (q==qcur ? acc : 0) + xv;  A[q][m][lane] = f2bf(acc)  (overwrite)
// Final LDS value per (dst,rel) = one bf16 rounding of the fp32 run sum ->
// numerics identical to the flush version. Then waves 0..3 do the 40-MFMA
// transform (round-4-verified layouts). mode 1: relu'd bf16; mode 2: fp32.
__global__ __launch_bounds__(512, 6) void fused_layer(
    const unsigned short* __restrict__ xb, const unsigned short* __restrict__ Wb,
    const int* __restrict__ edgedata, const int* __restrict__ off2,
    unsigned short* __restrict__ xbout, float* __restrict__ h2out, int mode) {
    __shared__ __align__(16) unsigned short A[NUM_RELS * 16 * PADR];  // 46080 B
    int wave = threadIdx.x >> 6, lane = threadIdx.x & 63;

    for (int i = threadIdx.x; i < NUM_RELS * 16 * PADR / 8; i += 512)
        ((int4*)A)[i] = (int4){0, 0, 0, 0};
    __syncthreads();

    int n0 = blockIdx.x * 16;
    int m0 = wave * 2, m1 = m0 + 1;
    int beg0 = off2[(n0 + m0) * NUM_RELS];
    int end0 = off2[(n0 + m0) * NUM_RELS + NUM_RELS];
    int beg1 = off2[(n0 + m1) * NUM_RELS];
    int end1 = off2[(n0 + m1) * NUM_RELS + NUM_RELS];
    int nf0 = (end0 - beg0) >> 3, nf1 = (end1 - beg1) >> 3;

    // prefetch first groups of BOTH walks up-front
    int pf0[8], pf1[8];
    if (nf0 > 0) {
#pragma unroll
        for (int j = 0; j < 8; ++j) pf0[j] = edgedata[beg0 + j];
    }
    if (nf1 > 0) {
#pragma unroll
        for (int j = 0; j < 8; ++j) pf1[j] = edgedata[beg1 + j];
    }

    auto walk = [&](int m, int beg, int end, int nfull, int (&pf)[8]) {
        int mbase = m * PADR + lane;           // ushort offset within a q-slab
        float acc = 0.f;
        int qcur = -1;
        int i = beg;
        int ew[8];
#pragma unroll
        for (int j = 0; j < 8; ++j) ew[j] = pf[j];
        for (int g = 0; g < nfull; ++g) {
            int ewc[8];
#pragma unroll
            for (int j = 0; j < 8; ++j) ewc[j] = ew[j];
            if (g + 1 < nfull) {
#pragma unroll
                for (int j = 0; j < 8; ++j) ew[j] = edgedata[i + 8 + j];
            }
            float xv[8];
#pragma unroll
            for (int j = 0; j < 8; ++j)
                xv[j] = bf2f(xb[(size_t)(ewc[j] & 0x1FFFF) * D + lane]);
#pragma unroll
            for (int j = 0; j < 8; ++j) {
                int q = ewc[j] >> 17;
                acc = (q == qcur ? acc : 0.f) + xv[j];
                A[q * (16 * PADR) + mbase] = f2bf(acc);
                qcur = q;
            }
            i += 8;
        }
        for (; i < end; ++i) {
            int ewc = edgedata[i];
            float xv = bf2f(xb[(size_t)(ewc & 0x1FFFF) * D + lane]);
            int q = ewc >> 17;
            acc = (q == qcur ? acc : 0.f) + xv;
            A[q * (16 * PADR) + mbase] = f2bf(acc);
            qcur = q;
        }
    };
    walk(m0, beg0, end0, nf0, pf0);
    walk(m1, beg1, end1, nf1, pf1);
    __syncthreads();

    if (wave < 4) {
        int lrow = lane & 15, lhi = lane >> 4;
        f32x4 C = {0.f, 0.f, 0.f, 0.f};
        for (int q = 0; q < NUM_RELS; ++q) {
            const unsigned short* Arow = &A[(q * 16 + lrow) * PADR + lhi * 8];
            bf16x8 a0 = *(const bf16x8*)(Arow);         // k = lhi*8 + j
            bf16x8 a1 = *(const bf16x8*)(Arow + 32);    // k = 32 + lhi*8 + j
            const unsigned short* wrow = Wb + ((size_t)q << 12)
                                         + (size_t)(wave * 16 + lrow) * D + lhi * 8;
            bf16x8 b0 = *(const bf16x8*)(wrow);
            bf16x8 b1 = *(const bf16x8*)(wrow + 32);
            C = __builtin_amdgcn_mfma_f32_16x16x32_bf16(a0, b0, C, 0, 0, 0);
            C = __builtin_amdgcn_mfma_f32_16x16x32_bf16(a1, b1, C, 0, 0, 0);
        }
        // C/D: row = lhi*4 + reg (dst-local), col = wave*16 + lrow
#pragma unroll
        for (int reg = 0; reg < 4; ++reg) {
            int node = n0 + lhi * 4 + reg;
            int col = wave * 16 + lrow;
            if (mode == 1)
                xbout[(size_t)node * D + col] = f2bf(fmaxf(C[reg], 0.f));
            else
                h2out[(size_t)node * D + col] = C[reg];
        }
    }
}

// ---------------- readout ----------------

__global__ void colsum_kernel(const float* __restrict__ h2,
                              float* __restrict__ g, int n) {
    __shared__ float s[256];
    int tid = threadIdx.x;
    int col = tid & 63;
    int rowgrp = (blockIdx.x * blockDim.x + tid) >> 6;
    int nrowgrp = (gridDim.x * blockDim.x) >> 6;
    float acc = 0.0f;
    for (int row = rowgrp; row < n; row += nrowgrp)
        acc += h2[(size_t)row * D + col];
    s[tid] = acc;
    __syncthreads();
    if (tid < 64) {
        acc = s[tid] + s[tid + 64] + s[tid + 128] + s[tid + 192];
        atomicAdd(&g[col], acc);
    }
}

__global__ void mlp_kernel(const float* __restrict__ g,
                           const float* __restrict__ A1w,
                           const float* __restrict__ A1b,
                           const float* __restrict__ A2w,
                           const float* __restrict__ A2b,
                           float* __restrict__ out, float invN) {
    __shared__ float a1[HID_ATTR];
    int t = threadIdx.x;
    if (t < HID_ATTR) {
        float acc = A1b[t];
#pragma unroll
        for (int d2 = 0; d2 < D; ++d2)
            acc = fmaf(g[d2] * invN, A1w[d2 * HID_ATTR + t], acc);
        a1[t] = fmaxf(acc, 0.0f);
    }
    __syncthreads();
    if (t < OUT_ATTR) {
        float acc = A2b[t];
#pragma unroll
        for (int j = 0; j < HID_ATTR; ++j)
            acc = fmaf(a1[j], A2w[j * OUT_ATTR + t], acc);
        out[t] = 1.0f / (1.0f + expf(-acc));
    }
}

// ---------------- launch ----------------

extern "C" void kernel_launch(void* const* d_in, const int* in_sizes, int n_in,
                              void* d_out, int out_size, void* d_ws, size_t ws_size,
                              hipStream_t stream) {
    const float* h   = (const float*)d_in[0];
    const int* src   = (const int*)d_in[1];
    const int* dst   = (const int*)d_in[2];
    const int* etype = (const int*)d_in[3];
    const float* W1  = (const float*)d_in[4];
    const float* W2  = (const float*)d_in[5];
    const float* A1w = (const float*)d_in[6];
    const float* A1b = (const float*)d_in[7];
    const float* A2w = (const float*)d_in[8];
    const float* A2b = (const float*)d_in[9];

    float* out_h2 = (float*)d_out;
    float* out_a  = out_h2 + (size_t)N_NODES * D;

    // workspace layout (int offsets from d_ws; all buffers 16B-aligned)
    int* base     = (int*)d_ws;
    float* gsum   = (float*)base;                 // 64 f32
    int* deg2     = base + 64;                    // 2,000,000
    int* off2     = base + 2000064;               // 2,000,001 (pad to 2,000,064)
    int* cur2     = base + 4000128;               // 2,000,000
    int* bsum2    = base + 6000128;               // 7,813 (pad 7,872)
    int* bbase2   = base + 6008000;               // 7,872
    int* edgedata = base + 6015872;               // 3,200,000
    unsigned short* xb  = (unsigned short*)(base + 9215872);   // 6.4M u16
    unsigned short* xb2 = (unsigned short*)(base + 12415872);  // 6.4M u16
    unsigned short* w1b = (unsigned short*)(base + 15615872);  // 81,920 u16
    unsigned short* w2b = (unsigned short*)(base + 15656832);  // 81,920 u16
    // total: 15,697,792 ints = 62.8 MB

    hipMemsetAsync(deg2, 0, (size_t)NKEYS * sizeof(int), stream);
    hipMemsetAsync(gsum, 0, 64 * sizeof(float), stream);

    // CSR sorted by (dst, rel)
    deg_count2<<<N_EDGES / 256, 256, 0, stream>>>(dst, etype, deg2);
    scan2_bsum<<<SCAN2_B, 256, 0, stream>>>(deg2, bsum2);
    scan2_bbase<<<1, 1024, 0, stream>>>(bsum2, bbase2, off2);
    scan2_final<<<SCAN2_B, 256, 0, stream>>>(deg2, bbase2, off2, cur2);
    scatter_edges2<<<N_EDGES / 256, 256, 0, stream>>>(src, dst, etype, cur2, edgedata);

    // conversions
    wconv_kernel<<<NUM_RELS, 256, 0, stream>>>(W1, w1b);
    wconv_kernel<<<NUM_RELS, 256, 0, stream>>>(W2, w2b);
    f2b_kernel<<<(N_NODES * D / 4 + 255) / 256, 256, 0, stream>>>(h, xb, N_NODES * D / 4);

    // two fused RGCN layers
    fused_layer<<<N_NODES / 16, 512, 0, stream>>>(xb, w1b, edgedata, off2,
                                                  xb2, nullptr, 1);
    fused_layer<<<N_NODES / 16, 512, 0, stream>>>(xb2, w2b, edgedata, off2,
                                                  nullptr, out_h2, 2);

    // readout
    colsum_kernel<<<512, 256, 0, stream>>>(out_h2, gsum, N_NODES);
    mlp_kernel<<<1, 64, 0, stream>>>(gsum, A1w, A1b, A2w, A2b,
                                     out_a, 1.0f / (float)N_NODES);
}